// Round 3
// 6815.762 us; speedup vs baseline: 1.0426x; 1.0426x over previous
//
#include <hip/hip_runtime.h>
#include <cstdio>

#define N_NODES 100000
#define NPAD    100096      // 782*128 padded row count (gemm reads full tiles)
#define NTILES  782         // ceil(100000/128)
#define NE      320000
#define NCH     196         // ceil(100000/512)
#define WCO_OFF 3145728L    // 6*256*2048 (inner W elems, quarter-Z layout)
#define OUT_ELEMS (N_NODES * 256)

typedef unsigned short ushort_t;
typedef unsigned short u16x4 __attribute__((ext_vector_type(4)));
typedef unsigned short u16x8 __attribute__((ext_vector_type(8)));
typedef _Float16       f16;
typedef _Float16       f16x8 __attribute__((ext_vector_type(8)));
typedef float          f32x4 __attribute__((ext_vector_type(4)));
typedef float          f32x4v __attribute__((ext_vector_type(4)));

__device__ __forceinline__ float bf2f(ushort_t u) {
    return __uint_as_float(((unsigned)u) << 16);
}
__device__ __forceinline__ ushort_t f2bf(float f) {
    unsigned u = __float_as_uint(f);
    u += 0x7FFFu + ((u >> 16) & 1u);   // round-to-nearest-even
    return (ushort_t)(u >> 16);
}
__device__ __forceinline__ ushort_t f2h(float f) {
    f16 h = (f16)f;
    return __builtin_bit_cast(ushort_t, h);
}
__device__ __forceinline__ float h2f(ushort_t u) {
    return (float)__builtin_bit_cast(f16, u);
}

// ---------------------------------------------------------------------------
// dtype sniff on embed_table words. flag = 1 means float32 inputs.
// ---------------------------------------------------------------------------
__global__ __launch_bounds__(256) void detect_k(const unsigned* __restrict__ w0, int* __restrict__ flag) {
    __shared__ int lds[256];
    int t = threadIdx.x;
    int cnt = 0;
    for (int i = t; i < 2048; i += 256) {
        unsigned e = (w0[i] >> 7) & 0xFFu;
        cnt += (e >= 96u && e <= 140u) ? 1 : 0;
    }
    lds[t] = cnt; __syncthreads();
    for (int s = 128; s > 0; s >>= 1) {
        if (t < s) lds[t] += lds[t + s];
        __syncthreads();
    }
    if (t == 0) *flag = (lds[0] < 1024) ? 1 : 0;
}

// input element -> canonical fp16 bits
__device__ __forceinline__ ushort_t load_in(const void* p, long i, bool isf32) {
    return isf32 ? f2h(((const float*)p)[i]) : f2h(bf2f(((const ushort_t*)p)[i]));
}

// ---------------------------------------------------------------------------
// small-tensor fp16 canonicalization (ln scales/biases, dense W/b)
// ---------------------------------------------------------------------------
struct CvtArgs {
    const void* src[8];
    ushort_t*   dst[8];
    int         n[8];
};

__global__ __launch_bounds__(256) void cvt_k(CvtArgs a, const int* __restrict__ flag) {
    int ti = blockIdx.y;
    int n = a.n[ti];
    const void* s = a.src[ti];
    ushort_t* d = a.dst[ti];
    bool isf32 = (*flag != 0);
    for (int i = blockIdx.x * 256 + threadIdx.x; i < n; i += gridDim.x * 256)
        d[i] = load_in(s, i, isf32);
}

// ---------------------------------------------------------------------------
// Weight pre-pack (dual dtype -> fp16).
// INNER (quarter-Z layout): per layer l, quarter q (output cols o = q*64+oo):
//   slab WC[l*524288 + q*131072 + n*256 + k], n in [0,512):
//     n = t*64 + oo        -> eWi[l][t][o][k]        (agg part, x_src)
//     n = 256 + t*64 + oo  -> eWi[l][t][o][256+k]    (self part, x_tgt)
// OUTER (unchanged G layout): Wcat[b*2+p][o, ts*2*din + j]
// ---------------------------------------------------------------------------
__global__ __launch_bounds__(256) void pack_w(const void* __restrict__ eWi,
                                              const void* __restrict__ eWo,
                                              ushort_t* __restrict__ WC,
                                              const int* __restrict__ flag) {
    long idx = (long)blockIdx.x * 256 + threadIdx.x;
    bool isf32 = (*flag != 0);
    const long ELI = 6L * 4 * 256 * 512;     // 3,145,728
    const long ELO = 2L * 4 * 512 * 1024;    // 4,194,304
    if (idx < ELI) {
        int j = idx & 511;
        int o = (idx >> 9) & 255;
        int t = (idx >> 17) & 3;
        long l = idx >> 19;
        int q = o >> 6, oo = o & 63;
        int k = j & 255;
        int n = ((j < 256) ? 0 : 256) + t * 64 + oo;
        WC[l * 524288 + (long)q * 131072 + (long)n * 256 + k] = load_in(eWi, idx, isf32);
    } else if (idx < ELI + ELO) {
        long i2 = idx - ELI;
        int j = i2 & 1023;
        int o = (i2 >> 10) & 511;
        int t = (i2 >> 19) & 3;
        long b = i2 >> 21;
        int p = t >> 1, ts = t & 1;
        WC[WCO_OFF + (b * 2 + p) * 1048576L + (long)o * 2048 + ts * 1024 + j] = load_in(eWo, i2, isf32);
    }
}

// ---------------------------------------------------------------------------
// Embedding gather (dual dtype): S[v] = fp16(table[ids[v]])
// ---------------------------------------------------------------------------
__global__ __launch_bounds__(256) void embed_k(const int* __restrict__ ids,
                                               const void* __restrict__ tab,
                                               ushort_t* __restrict__ S,
                                               const int* __restrict__ flag) {
    int row = blockIdx.x * 4 + (threadIdx.x >> 6);
    int l = threadIdx.x & 63;
    if (row >= N_NODES) return;
    int id = ids[row];
    u16x4 v;
    if (*flag) {
        f32x4v fv = *(const f32x4v*)((const float*)tab + (size_t)id * 256 + l * 4);
        #pragma unroll
        for (int i = 0; i < 4; i++) v[i] = f2h(fv[i]);
    } else {
        u16x4 bv = *(const u16x4*)((const ushort_t*)tab + (size_t)id * 256 + l * 4);
        #pragma unroll
        for (int i = 0; i < 4; i++) v[i] = f2h(bf2f(bv[i]));
    }
    *(u16x4*)(S + (size_t)row * 256 + l * 4) = v;
}

// ---------------------------------------------------------------------------
// Output emit: internal fp16 -> harness dtype (f32 or bf16)
// ---------------------------------------------------------------------------
__global__ __launch_bounds__(256) void emit_k(const ushort_t* __restrict__ Bst, void* __restrict__ out,
                                              const int* __restrict__ flag) {
    long i = (long)blockIdx.x * 256 + threadIdx.x;
    if (i >= OUT_ELEMS) return;
    float v = h2f(Bst[i]);
    if (*flag) ((float*)out)[i] = v;
    else       ((ushort_t*)out)[i] = f2bf(v);
}

// ---------------------------------------------------------------------------
// CSR by target node
// ---------------------------------------------------------------------------
__global__ __launch_bounds__(256) void count_k(const int* __restrict__ tgt, int* __restrict__ counts) {
    int e = blockIdx.x * 256 + threadIdx.x;
    if (e < NE) atomicAdd(&counts[tgt[e]], 1);
}

__global__ __launch_bounds__(256) void scan1_k(const int* __restrict__ counts,
                                               int* __restrict__ incl, int* __restrict__ chsums) {
    __shared__ int lds[256];
    int c = blockIdx.x, t = threadIdx.x;
    int i0 = c * 512 + 2 * t;
    int a = (i0 < N_NODES) ? counts[i0] : 0;
    int b = (i0 + 1 < N_NODES) ? counts[i0 + 1] : 0;
    int ps = a + b;
    lds[t] = ps; __syncthreads();
    int x = ps;
    for (int off = 1; off < 256; off <<= 1) {
        int y = (t >= off) ? lds[t - off] : 0;
        __syncthreads();
        x += y; lds[t] = x;
        __syncthreads();
    }
    int excl = x - ps;
    if (i0 < N_NODES) incl[i0] = excl + a;
    if (i0 + 1 < N_NODES) incl[i0 + 1] = excl + a + b;
    if (t == 255) chsums[c] = x;
}

__global__ __launch_bounds__(256) void scan2_k(const int* __restrict__ chsums, int* __restrict__ chunkoff) {
    __shared__ int lds[256];
    int t = threadIdx.x;
    int v = (t < NCH) ? chsums[t] : 0;
    lds[t] = v; __syncthreads();
    int x = v;
    for (int off = 1; off < 256; off <<= 1) {
        int y = (t >= off) ? lds[t - off] : 0;
        __syncthreads();
        x += y; lds[t] = x;
        __syncthreads();
    }
    if (t <= NCH) chunkoff[t] = x - v;   // exclusive
}

__global__ __launch_bounds__(256) void scan3_k(const int* __restrict__ counts, const int* __restrict__ incl,
                                               const int* __restrict__ chunkoff,
                                               int* __restrict__ offsets, int* __restrict__ cursor) {
    int c = blockIdx.x, t = threadIdx.x;
    int base = chunkoff[c];
    #pragma unroll
    for (int k = 0; k < 2; k++) {
        int i = c * 512 + 2 * t + k;
        if (i < N_NODES) {
            int off = base + incl[i] - counts[i];
            offsets[i] = off;
            cursor[i] = off;
        }
    }
    if (c == 0 && t == 0) offsets[N_NODES] = chunkoff[NCH];
}

__global__ __launch_bounds__(256) void fill_k(const int* __restrict__ et, const int* __restrict__ src,
                                              const int* __restrict__ tgt,
                                              int* __restrict__ cursor, int* __restrict__ sorted) {
    int e = blockIdx.x * 256 + threadIdx.x;
    if (e < NE) {
        int pos = atomicAdd(&cursor[tgt[e]], 1);
        sorted[pos] = ((et[e] - 1) << 28) | src[e];
    }
}

// ---------------------------------------------------------------------------
// build_G: wave per node, chunked. (OUT layers only, DIN=512.)
// ---------------------------------------------------------------------------
template<int DIN>
__device__ __forceinline__ void load_row(const ushort_t* __restrict__ X0, const ushort_t* __restrict__ X1,
                                         size_t r, int l, float* out) {
    if constexpr (DIN == 256) {
        u16x4 rv = *(const u16x4*)(X0 + r * 256 + l * 4);
        #pragma unroll
        for (int i = 0; i < 4; i++) out[i] = h2f(rv[i]);
    } else {
        const ushort_t* bp = (l < 32) ? (X0 + r * 256 + (size_t)l * 8)
                                      : (X1 + r * 256 + (size_t)(l - 32) * 8);
        u16x8 rv = *(const u16x8*)bp;
        #pragma unroll
        for (int i = 0; i < 8; i++) out[i] = h2f(rv[i]);
    }
}

template<int DIN>
__device__ __forceinline__ void store_blk(ushort_t* __restrict__ G, size_t base, int l,
                                          const float* A, int D, const float* xv) {
    if constexpr (DIN == 256) {
        u16x4 o1, o2;
        #pragma unroll
        for (int i = 0; i < 4; i++) { o1[i] = f2h(A[i]); o2[i] = f2h((float)D * xv[i]); }
        *(u16x4*)(G + base + l * 4) = o1;
        *(u16x4*)(G + base + DIN + l * 4) = o2;
    } else {
        u16x8 o1, o2;
        #pragma unroll
        for (int i = 0; i < 8; i++) { o1[i] = f2h(A[i]); o2[i] = f2h((float)D * xv[i]); }
        *(u16x8*)(G + base + l * 8) = o1;
        *(u16x8*)(G + base + DIN + l * 8) = o2;
    }
}

template<int DIN, int NT>
__global__ __launch_bounds__(256) void build_g(const ushort_t* __restrict__ X0, const ushort_t* __restrict__ X1,
                                               const int* __restrict__ offsets, const int* __restrict__ sorted,
                                               ushort_t* __restrict__ G, int t0, int vbase) {
    constexpr int VPL = DIN / 64;
    int vl = blockIdx.x * 4 + (threadIdx.x >> 6);
    int l = threadIdx.x & 63;
    int v = vbase + vl;
    float a0[VPL] = {}, a1[VPL] = {}, a2[VPL] = {}, a3[VPL] = {};
    int d0 = 0, d1 = 0, d2 = 0, d3 = 0;
    float xv[VPL];
    #pragma unroll
    for (int i = 0; i < VPL; i++) xv[i] = 0.f;
    if (v < N_NODES) {
        int beg = offsets[v], end = offsets[v + 1];
        for (int e = beg; e < end; ++e) {
            int pk = sorted[e];
            int t = (pk >> 28) - t0;
            if ((unsigned)t >= (unsigned)NT) continue;
            int s = pk & 0x0FFFFFFF;
            float rvf[VPL];
            load_row<DIN>(X0, X1, (size_t)s, l, rvf);
            if (t == 0) { d0++;
                #pragma unroll
                for (int i = 0; i < VPL; i++) a0[i] += rvf[i]; }
            else if (t == 1) { d1++;
                #pragma unroll
                for (int i = 0; i < VPL; i++) a1[i] += rvf[i]; }
            else if (NT > 2 && t == 2) { d2++;
                #pragma unroll
                for (int i = 0; i < VPL; i++) a2[i] += rvf[i]; }
            else { d3++;
                #pragma unroll
                for (int i = 0; i < VPL; i++) a3[i] += rvf[i]; }
        }
        load_row<DIN>(X0, X1, (size_t)v, l, xv);
    }
    size_t rowb = (size_t)vl * 2048;
    store_blk<DIN>(G, rowb + 0 * 2 * DIN, l, a0, d0, xv);
    store_blk<DIN>(G, rowb + 1 * 2 * DIN, l, a1, d1, xv);
    if constexpr (NT > 2) {
        store_blk<DIN>(G, rowb + 2 * 2 * DIN, l, a2, d2, xv);
        store_blk<DIN>(G, rowb + 3 * 2 * DIN, l, a3, d3, xv);
    }
}

// ---------------------------------------------------------------------------
// GEMM: C[localM, ldc] = A[localM, K] @ B[., K]^T  (fp16 row-major)
// 128x128 tile, BK=64, 4 waves, mfma_f32_16x16x32_f16, global_load_lds(16B).
// EPI 0: Cf = acc   EPI 1: Cf += acc
// EPI 2: Cb[r*ldc+c] = fp16(tanh(acc + bias[c])), local rows < storeM only
// EPI 3: Cb[r*ldc+c] = fp16(acc)                (Z emit, unguarded/padded)
// ---------------------------------------------------------------------------
template<int EPI>
__global__ __launch_bounds__(256) void gemm_bt(const ushort_t* __restrict__ A,
                                               const ushort_t* __restrict__ B,
                                               int K, int ldc,
                                               float* __restrict__ Cf, ushort_t* __restrict__ Cb,
                                               const ushort_t* __restrict__ bias, int storeM) {
    __shared__ __align__(16) ushort_t As[128 * 64];
    __shared__ __align__(16) ushort_t Bs[128 * 64];
    const int tid = threadIdx.x;
    const int w = tid >> 6, l = tid & 63;
    const int wr = w >> 1, wc = w & 1;
    const long m0 = (long)blockIdx.y * 128, n0 = (long)blockIdx.x * 128;
    const int lr = l >> 3;
    const int lc = (l & 7) * 8;
    f32x4 acc[4][4];
    #pragma unroll
    for (int s = 0; s < 4; s++)
        #pragma unroll
        for (int n = 0; n < 4; n++) acc[s][n] = (f32x4){0.f, 0.f, 0.f, 0.f};

    for (int k0 = 0; k0 < K; k0 += 64) {
        #pragma unroll
        for (int q = 0; q < 4; q++) {
            int row = w * 32 + q * 8 + lr;
            const ushort_t* g = A + (m0 + row) * (long)K + k0 + lc;
            __builtin_amdgcn_global_load_lds(
                (__attribute__((address_space(1))) unsigned int*)(g),
                (__attribute__((address_space(3))) unsigned int*)(&As[row * 64 + lc]), 16, 0, 0);
        }
        #pragma unroll
        for (int q = 0; q < 4; q++) {
            int row = w * 32 + q * 8 + lr;
            const ushort_t* g = B + (n0 + row) * (long)K + k0 + lc;
            __builtin_amdgcn_global_load_lds(
                (__attribute__((address_space(1))) unsigned int*)(g),
                (__attribute__((address_space(3))) unsigned int*)(&Bs[row * 64 + lc]), 16, 0, 0);
        }
        __syncthreads();
        #pragma unroll
        for (int kk = 0; kk < 2; kk++) {
            f16x8 af[4], bfr[4];
            #pragma unroll
            for (int s = 0; s < 4; s++)
                af[s] = *(const f16x8*)&As[(wr * 64 + s * 16 + (l & 15)) * 64 + kk * 32 + (l >> 4) * 8];
            #pragma unroll
            for (int n = 0; n < 4; n++)
                bfr[n] = *(const f16x8*)&Bs[(wc * 64 + n * 16 + (l & 15)) * 64 + kk * 32 + (l >> 4) * 8];
            #pragma unroll
            for (int s = 0; s < 4; s++)
                #pragma unroll
                for (int n = 0; n < 4; n++)
                    acc[s][n] = __builtin_amdgcn_mfma_f32_16x16x32_f16(af[s], bfr[n], acc[s][n], 0, 0, 0);
        }
        __syncthreads();
    }
    const long rb = m0 + wr * 64 + ((l >> 4) << 2);
    const long cb = n0 + wc * 64 + (l & 15);
    #pragma unroll
    for (int s = 0; s < 4; s++) {
        #pragma unroll
        for (int n = 0; n < 4; n++) {
            long c = cb + n * 16;
            #pragma unroll
            for (int j = 0; j < 4; j++) {
                long r = rb + s * 16 + j;
                float val = acc[s][n][j];
                if constexpr (EPI == 0) {
                    Cf[r * ldc + c] = val;
                } else if constexpr (EPI == 1) {
                    Cf[r * ldc + c] += val;
                } else if constexpr (EPI == 2) {
                    if (r < storeM) {
                        float t = tanhf(val + h2f(bias[c]));
                        Cb[r * ldc + c] = f2h(t);
                    }
                } else {
                    Cb[r * ldc + c] = f2h(val);
                }
            }
        }
    }
}

// ---------------------------------------------------------------------------
// Quarter-aggregate over Z_q (inner layers). Z_q[u, n] fp16, n in [0,512):
//   n = t*64 + oo (agg), 256 + t*64 + oo (self), oo = output col within quarter.
// Magg[v, q*64+oo] = sum_{e:tgt=v} Z_q[src_e, t_e*64+oo]
//                  + sum_t D_t(v) * Z_q[v, 256+t*64+oo]
// Wave per node, lane = oo. Z_q is L3-resident (102.5 MB, just written).
// ---------------------------------------------------------------------------
__global__ __launch_bounds__(256) void agg_q(const ushort_t* __restrict__ Z,
                                             const int* __restrict__ offsets,
                                             const int* __restrict__ sorted,
                                             ushort_t* __restrict__ Magg, int q) {
    int v = blockIdx.x * 4 + (threadIdx.x >> 6);
    int l = threadIdx.x & 63;
    if (v >= NPAD) return;
    ushort_t* mp = Magg + (size_t)v * 256 + (q << 6) + l;
    if (v >= N_NODES) { *mp = 0; return; }
    float acc = 0.f;
    int d0 = 0, d1 = 0, d2 = 0, d3 = 0;
    int beg = offsets[v], end = offsets[v + 1];
    for (int e = beg; e < end; ++e) {
        int pk = sorted[e];
        int t = pk >> 28;                 // 0..3
        int s = pk & 0x0FFFFFFF;
        acc += h2f(Z[(size_t)s * 512 + (t << 6) + l]);
        d0 += (t == 0); d1 += (t == 1); d2 += (t == 2); d3 += (t == 3);
    }
    const ushort_t* zs = Z + (size_t)v * 512 + 256 + l;
    if (d0) acc += (float)d0 * h2f(zs[0]);
    if (d1) acc += (float)d1 * h2f(zs[64]);
    if (d2) acc += (float)d2 * h2f(zs[128]);
    if (d3) acc += (float)d3 * h2f(zs[192]);
    *mp = f2h(acc);
}

// ---------------------------------------------------------------------------
// gelu + LN from fp16 Magg (inner layers, 256 cols). Wave per row.
// ---------------------------------------------------------------------------
__global__ __launch_bounds__(256) void gelu_ln16_k(const ushort_t* __restrict__ M,
                                                   const ushort_t* __restrict__ ls,
                                                   const ushort_t* __restrict__ lb,
                                                   ushort_t* __restrict__ H) {
    int row = blockIdx.x * 4 + (threadIdx.x >> 6);
    int l = threadIdx.x & 63;
    u16x4 mv = *(const u16x4*)(M + (size_t)row * 256 + l * 4);
    float g[4];
    float s = 0.f, q = 0.f;
    #pragma unroll
    for (int i = 0; i < 4; i++) {
        float x = h2f(mv[i]);
        float gg = 0.5f * x * (1.f + erff(x * 0.70710678118654752f));
        g[i] = gg; s += gg; q += gg * gg;
    }
    #pragma unroll
    for (int m = 1; m < 64; m <<= 1) {
        s += __shfl_xor(s, m, 64);
        q += __shfl_xor(q, m, 64);
    }
    float mean = s * (1.f / 256.f);
    float var = q * (1.f / 256.f) - mean * mean;
    var = fmaxf(var, 0.f);
    float rs = rsqrtf(var + 1e-5f);
    int col = l << 2;
    u16x4 o;
    #pragma unroll
    for (int i = 0; i < 4; i++)
        o[i] = f2h((g[i] - mean) * rs * h2f(ls[col + i]) + h2f(lb[col + i]));
    *(u16x4*)(H + (size_t)row * 256 + col) = o;
}

// ---------------------------------------------------------------------------
// gelu + LayerNorm from f32, wave per local row. (OUT layers, DOUT=512.)
// ---------------------------------------------------------------------------
template<int DOUT>
__global__ __launch_bounds__(256) void gelu_ln_k(const float* __restrict__ Mf,
                                                 const ushort_t* __restrict__ ls,
                                                 const ushort_t* __restrict__ lb,
                                                 ushort_t* __restrict__ H) {
    constexpr int VPL = DOUT / 64;
    int row = blockIdx.x * 4 + (threadIdx.x >> 6);
    int l = threadIdx.x & 63;
    const float* p = Mf + (size_t)row * DOUT + l * VPL;
    float g[VPL];
    float s = 0.f, q = 0.f;
    #pragma unroll
    for (int i = 0; i < VPL; i++) {
        float x = p[i];
        float gg = 0.5f * x * (1.f + erff(x * 0.70710678118654752f));
        g[i] = gg; s += gg; q += gg * gg;
    }
    #pragma unroll
    for (int m = 1; m < 64; m <<= 1) {
        s += __shfl_xor(s, m, 64);
        q += __shfl_xor(q, m, 64);
    }
    float mean = s * (1.f / DOUT);
    float var = q * (1.f / DOUT) - mean * mean;
    var = fmaxf(var, 0.f);
    float rs = rsqrtf(var + 1e-5f);
    ushort_t* hp = H + (size_t)row * DOUT + l * VPL;
    #pragma unroll
    for (int i = 0; i < VPL; i++) {
        int col = l * VPL + i;
        hp[i] = f2h((g[i] - mean) * rs * h2f(ls[col]) + h2f(lb[col]));
    }
}

// ---------------------------------------------------------------------------
extern "C" void kernel_launch(void* const* d_in, const int* in_sizes, int n_in,
                              void* d_out, int out_size, void* d_ws, size_t ws_size,
                              hipStream_t stream) {
    const int* ids = (const int*)d_in[0];
    const int* te = (const int*)d_in[1];
    const int* et = te;
    const int* esrc = te + NE;
    const int* etgt = te + 2 * NE;
    const void* tab = d_in[2];
    const void* eWi = d_in[3];
    const void* lsi = d_in[4];
    const void* lbi = d_in[5];
    const void* dWi = d_in[6];
    const void* dbi = d_in[7];
    const void* eWo = d_in[8];
    const void* lso = d_in[9];
    const void* lbo = d_in[10];
    const void* dWo = d_in[11];
    const void* dbo = d_in[12];

    char* w = (char*)d_ws;
    auto alloc = [&](size_t bytes) -> char* {
        char* p = w; w += (bytes + 255) & ~(size_t)255; return p;
    };
    ushort_t* A    = (ushort_t*)alloc((size_t)NPAD * 256 * 2);      // 51.25 MB
    ushort_t* Bst  = (ushort_t*)alloc((size_t)NPAD * 256 * 2);      // 51.25 MB
    ushort_t* WC   = (ushort_t*)alloc(7340032UL * 2);               // 14.7 MB
    ushort_t* lsiC = (ushort_t*)alloc(1536 * 2);
    ushort_t* lbiC = (ushort_t*)alloc(1536 * 2);
    ushort_t* dbiC = (ushort_t*)alloc(1536 * 2);
    ushort_t* lsoC = (ushort_t*)alloc(1024 * 2);
    ushort_t* lboC = (ushort_t*)alloc(1024 * 2);
    ushort_t* dboC = (ushort_t*)alloc(512 * 2);
    ushort_t* dWiC = (ushort_t*)alloc(393216UL * 2);
    ushort_t* dWoC = (ushort_t*)alloc(262144UL * 2);
    int* flag      = (int*)alloc(256);
    int* counts    = (int*)alloc((size_t)N_NODES * 4);
    int* incl      = (int*)alloc((size_t)N_NODES * 4);
    int* chsums    = (int*)alloc(1024);
    int* chunkoff  = (int*)alloc(1024);
    int* offsets   = (int*)alloc((size_t)(N_NODES + 8) * 4);
    int* cursor    = (int*)alloc((size_t)N_NODES * 4);
    int* sorted    = (int*)alloc((size_t)NE * 4);
    ushort_t* Magg = (ushort_t*)alloc((size_t)NPAD * 256 * 2);      // 51.25 MB (msg, fp16)
    // Third state buffer: prefer d_out (f32 harness -> 102.4 MB), else ws.
    ushort_t* R;
    if ((size_t)out_size >= (size_t)NPAD * 256 * 2) R = (ushort_t*)d_out;
    else R = (ushort_t*)alloc((size_t)NPAD * 256 * 2);
    size_t fixed = (size_t)(w - (char*)d_ws);

    // Big shared scratch: inner {Z_q 102.5 MB, then H_in 51.25 MB} / out {G,Mf,Hc chunks}
    const size_t ZQ_BYTES = (size_t)NPAD * 512 * 2;                 // 102,498,304
    const size_t PER_TILE = 128UL * 2048 * 2 + 128UL * 512 * 4 + 128UL * 512 * 2;  // 917,504
    size_t bigsz = (ws_size > fixed) ? (ws_size - fixed) : 0;
    long tiles_chunk = (long)(bigsz / PER_TILE);
    if (tiles_chunk > NTILES) tiles_chunk = NTILES;
    if (bigsz < ZQ_BYTES || tiles_chunk < 1) {
        fprintf(stderr, "kernel_launch: ws too small (%zu bytes, fixed %zu, big %zu) -- no-op\n",
                ws_size, fixed, bigsz);
        return;
    }
    char* big = w;                       // rest of workspace
    ushort_t* Zq   = (ushort_t*)big;                                 // inner: [NPAD,512] fp16
    ushort_t* Hin  = (ushort_t*)big;                                 // inner: [NPAD,256] fp16 (after Zq dead)
    ushort_t* G    = (ushort_t*)big;                                 // out: chunk G
    float*    Mf   = (float*)(big + (size_t)tiles_chunk * 524288);   // out: chunk Mf
    ushort_t* Hc   = (ushort_t*)(big + (size_t)tiles_chunk * (524288 + 262144)); // out: chunk H

    // ---- setup: dtype detect, canonicalize, CSR, embed, weight pack ----
    detect_k<<<1, 256, 0, stream>>>((const unsigned*)tab, flag);
    CvtArgs ca;
    ca.src[0] = lsi;  ca.dst[0] = lsiC; ca.n[0] = 1536;
    ca.src[1] = lbi;  ca.dst[1] = lbiC; ca.n[1] = 1536;
    ca.src[2] = dbi;  ca.dst[2] = dbiC; ca.n[2] = 1536;
    ca.src[3] = lso;  ca.dst[3] = lsoC; ca.n[3] = 1024;
    ca.src[4] = lbo;  ca.dst[4] = lboC; ca.n[4] = 1024;
    ca.src[5] = dbo;  ca.dst[5] = dboC; ca.n[5] = 512;
    ca.src[6] = dWi;  ca.dst[6] = dWiC; ca.n[6] = 393216;
    ca.src[7] = dWo;  ca.dst[7] = dWoC; ca.n[7] = 262144;
    cvt_k<<<dim3(1536, 8), 256, 0, stream>>>(ca, flag);
    hipMemsetAsync(counts, 0, (size_t)N_NODES * 4, stream);
    // zero pad rows (100000..100095) of the three state buffers once
    hipMemsetAsync(A   + (size_t)N_NODES * 256, 0, (size_t)(NPAD - N_NODES) * 256 * 2, stream);
    hipMemsetAsync(Bst + (size_t)N_NODES * 256, 0, (size_t)(NPAD - N_NODES) * 256 * 2, stream);
    hipMemsetAsync(R   + (size_t)N_NODES * 256, 0, (size_t)(NPAD - N_NODES) * 256 * 2, stream);
    pack_w<<<28672, 256, 0, stream>>>(eWi, eWo, WC, flag);
    embed_k<<<N_NODES / 4, 256, 0, stream>>>(ids, tab, A, flag);
    count_k<<<(NE + 255) / 256, 256, 0, stream>>>(etgt, counts);
    scan1_k<<<NCH, 256, 0, stream>>>(counts, incl, chsums);
    scan2_k<<<1, 256, 0, stream>>>(chsums, chunkoff);
    scan3_k<<<NCH, 256, 0, stream>>>(counts, incl, chunkoff, offsets, cursor);
    fill_k<<<(NE + 255) / 256, 256, 0, stream>>>(et, esrc, etgt, cursor, sorted);

    // ---- inner layer (transform-then-aggregate, quarter-chunked Z) ----
    auto inner_layer = [&](const ushort_t* Xin, ushort_t* Xout, int lay) {
        for (int q = 0; q < 4; q++) {
            // Z_q = Xin @ Wq^T : [NPAD x 512] fp16 (L3-resident for the agg pass)
            gemm_bt<3><<<dim3(4, NTILES), 256, 0, stream>>>(
                Xin, WC + (long)lay * 524288 + (long)q * 131072, 256, 512,
                nullptr, Zq, nullptr, 0);
            agg_q<<<NPAD / 4, 256, 0, stream>>>(Zq, offsets, sorted, Magg, q);
        }
        gelu_ln16_k<<<NPAD / 4, 256, 0, stream>>>(Magg, lsiC + lay * 256, lbiC + lay * 256, Hin);
        gemm_bt<2><<<dim3(2, NTILES), 256, 0, stream>>>(Hin, dWiC + (long)lay * 65536, 256, 256,
                                                        nullptr, Xout, dbiC + lay * 256, N_NODES);
    };

    // ---- out layer (unchanged G-based path, chunked in big region) ----
    auto out_layer = [&](const ushort_t* X0, const ushort_t* X1, int b, ushort_t* dest) {
        for (long t0t = 0; t0t < NTILES; t0t += tiles_chunk) {
            long tc = NTILES - t0t; if (tc > tiles_chunk) tc = tiles_chunk;
            long rows = tc * 128, mb = t0t * 128;
            build_g<512, 2><<<rows / 4, 256, 0, stream>>>(X0, X1, offsets, sorted, G, 0, (int)mb);
            gemm_bt<0><<<dim3(4, tc), 256, 0, stream>>>(G, WC + WCO_OFF + (long)(b * 2 + 0) * 1048576,
                                                        2048, 512, Mf, nullptr, nullptr, 0);
            build_g<512, 2><<<rows / 4, 256, 0, stream>>>(X0, X1, offsets, sorted, G, 2, (int)mb);
            gemm_bt<1><<<dim3(4, tc), 256, 0, stream>>>(G, WC + WCO_OFF + (long)(b * 2 + 1) * 1048576,
                                                        2048, 512, Mf, nullptr, nullptr, 0);
            gelu_ln_k<512><<<rows / 4, 256, 0, stream>>>(Mf, lsoC + b * 512, lboC + b * 512, Hc);
            long sM = (long)N_NODES - mb; if (sM > rows) sM = rows; if (sM < 0) sM = 0;
            gemm_bt<2><<<dim3(2, tc), 256, 0, stream>>>(Hc, dWoC + (long)b * 131072, 512, 256,
                                                        nullptr, dest + mb * 256, dboC + b * 256, (int)sM);
        }
    };

    // block 0: state A (embed). inner: A->Bst, Bst->R, R->Bst. out [A|Bst] -> R
    inner_layer(A, Bst, 0);
    inner_layer(Bst, R, 1);
    inner_layer(R, Bst, 2);
    out_layer(A, Bst, 0, R);
    // block 1: state R. inner: R->A, A->Bst, Bst->A. out [R|A] -> Bst
    inner_layer(R, A, 3);
    inner_layer(A, Bst, 4);
    inner_layer(Bst, A, 5);
    out_layer(R, A, 1, Bst);

    emit_k<<<(OUT_ELEMS + 255) / 256, 256, 0, stream>>>(Bst, d_out, flag);
}

// Round 4
// 6489.485 us; speedup vs baseline: 1.0951x; 1.0503x over previous
//
#include <hip/hip_runtime.h>
#include <cstdio>

#define N_NODES 100000
#define NPAD    100096      // 782*128 padded row count (gemm reads full tiles)
#define NTILES  782         // ceil(100000/128)
#define NE      320000
#define NCH     196         // ceil(100000/512)
#define WCO_OFF 3145728L    // 6*256*2048 inner W elems (quarter-Z layout)
#define OUT_ELEMS (N_NODES * 256)

typedef unsigned short ushort_t;
typedef unsigned short u16x4 __attribute__((ext_vector_type(4)));
typedef unsigned short u16x8 __attribute__((ext_vector_type(8)));
typedef _Float16       f16;
typedef _Float16       f16x8 __attribute__((ext_vector_type(8)));
typedef float          f32x4 __attribute__((ext_vector_type(4)));
typedef float          f32x4v __attribute__((ext_vector_type(4)));

__device__ __forceinline__ float bf2f(ushort_t u) {
    return __uint_as_float(((unsigned)u) << 16);
}
__device__ __forceinline__ ushort_t f2bf(float f) {
    unsigned u = __float_as_uint(f);
    u += 0x7FFFu + ((u >> 16) & 1u);   // round-to-nearest-even
    return (ushort_t)(u >> 16);
}
__device__ __forceinline__ ushort_t f2h(float f) {
    f16 h = (f16)f;
    return __builtin_bit_cast(ushort_t, h);
}
__device__ __forceinline__ float h2f(ushort_t u) {
    return (float)__builtin_bit_cast(f16, u);
}

// ---------------------------------------------------------------------------
// dtype sniff on embed_table words. flag = 1 means float32 inputs.
// ---------------------------------------------------------------------------
__global__ __launch_bounds__(256) void detect_k(const unsigned* __restrict__ w0, int* __restrict__ flag) {
    __shared__ int lds[256];
    int t = threadIdx.x;
    int cnt = 0;
    for (int i = t; i < 2048; i += 256) {
        unsigned e = (w0[i] >> 7) & 0xFFu;
        cnt += (e >= 96u && e <= 140u) ? 1 : 0;
    }
    lds[t] = cnt; __syncthreads();
    for (int s = 128; s > 0; s >>= 1) {
        if (t < s) lds[t] += lds[t + s];
        __syncthreads();
    }
    if (t == 0) *flag = (lds[0] < 1024) ? 1 : 0;
}

// input element -> canonical fp16 bits
__device__ __forceinline__ ushort_t load_in(const void* p, long i, bool isf32) {
    return isf32 ? f2h(((const float*)p)[i]) : f2h(bf2f(((const ushort_t*)p)[i]));
}

// ---------------------------------------------------------------------------
// small-tensor fp16 canonicalization (ln scales/biases, dense W/b)
// ---------------------------------------------------------------------------
struct CvtArgs {
    const void* src[8];
    ushort_t*   dst[8];
    int         n[8];
};

__global__ __launch_bounds__(256) void cvt_k(CvtArgs a, const int* __restrict__ flag) {
    int ti = blockIdx.y;
    int n = a.n[ti];
    const void* s = a.src[ti];
    ushort_t* d = a.dst[ti];
    bool isf32 = (*flag != 0);
    for (int i = blockIdx.x * 256 + threadIdx.x; i < n; i += gridDim.x * 256)
        d[i] = load_in(s, i, isf32);
}

// ---------------------------------------------------------------------------
// Weight pre-pack (dual dtype -> fp16), both stacks in quarter-Z layout.
// INNER: layer l, chunk q (out cols o = q*64+oo), slab WC[l*524288 + q*131072
//   + n*256 + k], n in [0,512): n = t*64+oo (agg, j=k<256) ; 256+t*64+oo (self, j=256+k)
// OUTER: block b, chunk c (out cols o = c*64+oo), slab WC[WCO_OFF + b*2097152
//   + c*262144 + n*512 + k], n in [0,512): n = t*64+oo (agg/src, j=k<512) ;
//   256+t*64+oo (self/tgt, j=512+k)
// ---------------------------------------------------------------------------
__global__ __launch_bounds__(256) void pack_w(const void* __restrict__ eWi,
                                              const void* __restrict__ eWo,
                                              ushort_t* __restrict__ WC,
                                              const int* __restrict__ flag) {
    long idx = (long)blockIdx.x * 256 + threadIdx.x;
    bool isf32 = (*flag != 0);
    const long ELI = 6L * 4 * 256 * 512;     // 3,145,728
    const long ELO = 2L * 4 * 512 * 1024;    // 4,194,304
    if (idx < ELI) {
        int j = idx & 511;
        int o = (idx >> 9) & 255;
        int t = (idx >> 17) & 3;
        long l = idx >> 19;
        int q = o >> 6, oo = o & 63;
        int k = j & 255;
        int n = ((j < 256) ? 0 : 256) + t * 64 + oo;
        WC[l * 524288 + (long)q * 131072 + (long)n * 256 + k] = load_in(eWi, idx, isf32);
    } else if (idx < ELI + ELO) {
        long i2 = idx - ELI;
        int j = i2 & 1023;
        int o = (i2 >> 10) & 511;
        int t = (i2 >> 19) & 3;
        long b = i2 >> 21;
        int c = o >> 6, oo = o & 63;
        int k = j & 511;
        int n = ((j < 512) ? 0 : 256) + t * 64 + oo;
        WC[WCO_OFF + b * 2097152L + (long)c * 262144 + (long)n * 512 + k] = load_in(eWo, i2, isf32);
    }
}

// ---------------------------------------------------------------------------
// Embedding gather (dual dtype): S[v] = fp16(table[ids[v]])
// ---------------------------------------------------------------------------
__global__ __launch_bounds__(256) void embed_k(const int* __restrict__ ids,
                                               const void* __restrict__ tab,
                                               ushort_t* __restrict__ S,
                                               const int* __restrict__ flag) {
    int row = blockIdx.x * 4 + (threadIdx.x >> 6);
    int l = threadIdx.x & 63;
    if (row >= N_NODES) return;
    int id = ids[row];
    u16x4 v;
    if (*flag) {
        f32x4v fv = *(const f32x4v*)((const float*)tab + (size_t)id * 256 + l * 4);
        #pragma unroll
        for (int i = 0; i < 4; i++) v[i] = f2h(fv[i]);
    } else {
        u16x4 bv = *(const u16x4*)((const ushort_t*)tab + (size_t)id * 256 + l * 4);
        #pragma unroll
        for (int i = 0; i < 4; i++) v[i] = f2h(bf2f(bv[i]));
    }
    *(u16x4*)(S + (size_t)row * 256 + l * 4) = v;
}

// ---------------------------------------------------------------------------
// Output emit: internal fp16 -> harness dtype (f32 or bf16)
// ---------------------------------------------------------------------------
__global__ __launch_bounds__(256) void emit_k(const ushort_t* __restrict__ Bst, void* __restrict__ out,
                                              const int* __restrict__ flag) {
    long i = (long)blockIdx.x * 256 + threadIdx.x;
    if (i >= OUT_ELEMS) return;
    float v = h2f(Bst[i]);
    if (*flag) ((float*)out)[i] = v;
    else       ((ushort_t*)out)[i] = f2bf(v);
}

// ---------------------------------------------------------------------------
// CSR by target node
// ---------------------------------------------------------------------------
__global__ __launch_bounds__(256) void count_k(const int* __restrict__ tgt, int* __restrict__ counts) {
    int e = blockIdx.x * 256 + threadIdx.x;
    if (e < NE) atomicAdd(&counts[tgt[e]], 1);
}

__global__ __launch_bounds__(256) void scan1_k(const int* __restrict__ counts,
                                               int* __restrict__ incl, int* __restrict__ chsums) {
    __shared__ int lds[256];
    int c = blockIdx.x, t = threadIdx.x;
    int i0 = c * 512 + 2 * t;
    int a = (i0 < N_NODES) ? counts[i0] : 0;
    int b = (i0 + 1 < N_NODES) ? counts[i0 + 1] : 0;
    int ps = a + b;
    lds[t] = ps; __syncthreads();
    int x = ps;
    for (int off = 1; off < 256; off <<= 1) {
        int y = (t >= off) ? lds[t - off] : 0;
        __syncthreads();
        x += y; lds[t] = x;
        __syncthreads();
    }
    int excl = x - ps;
    if (i0 < N_NODES) incl[i0] = excl + a;
    if (i0 + 1 < N_NODES) incl[i0 + 1] = excl + a + b;
    if (t == 255) chsums[c] = x;
}

__global__ __launch_bounds__(256) void scan2_k(const int* __restrict__ chsums, int* __restrict__ chunkoff) {
    __shared__ int lds[256];
    int t = threadIdx.x;
    int v = (t < NCH) ? chsums[t] : 0;
    lds[t] = v; __syncthreads();
    int x = v;
    for (int off = 1; off < 256; off <<= 1) {
        int y = (t >= off) ? lds[t - off] : 0;
        __syncthreads();
        x += y; lds[t] = x;
        __syncthreads();
    }
    if (t <= NCH) chunkoff[t] = x - v;   // exclusive
}

__global__ __launch_bounds__(256) void scan3_k(const int* __restrict__ counts, const int* __restrict__ incl,
                                               const int* __restrict__ chunkoff,
                                               int* __restrict__ offsets, int* __restrict__ cursor) {
    int c = blockIdx.x, t = threadIdx.x;
    int base = chunkoff[c];
    #pragma unroll
    for (int k = 0; k < 2; k++) {
        int i = c * 512 + 2 * t + k;
        if (i < N_NODES) {
            int off = base + incl[i] - counts[i];
            offsets[i] = off;
            cursor[i] = off;
        }
    }
    if (c == 0 && t == 0) offsets[N_NODES] = chunkoff[NCH];
}

__global__ __launch_bounds__(256) void fill_k(const int* __restrict__ et, const int* __restrict__ src,
                                              const int* __restrict__ tgt,
                                              int* __restrict__ cursor, int* __restrict__ sorted) {
    int e = blockIdx.x * 256 + threadIdx.x;
    if (e < NE) {
        int pos = atomicAdd(&cursor[tgt[e]], 1);
        sorted[pos] = ((et[e] - 1) << 28) | src[e];
    }
}

// ---------------------------------------------------------------------------
// GEMM: C[localM, ldc] = A[localM, K] @ B[., K]^T  (fp16 row-major)
// 128x128 tile, BK=64, 4 waves, mfma_f32_16x16x32_f16, global_load_lds(16B).
// EPI 2: Cb[r*ldc+c] = fp16(tanh(acc + bias[c])), local rows < storeM only
// EPI 3: Cb[r*ldc+c] = fp16(acc)                (Z emit, unguarded/padded)
// ---------------------------------------------------------------------------
template<int EPI>
__global__ __launch_bounds__(256) void gemm_bt(const ushort_t* __restrict__ A,
                                               const ushort_t* __restrict__ B,
                                               int K, int ldc,
                                               ushort_t* __restrict__ Cb,
                                               const ushort_t* __restrict__ bias, int storeM) {
    __shared__ __align__(16) ushort_t As[128 * 64];
    __shared__ __align__(16) ushort_t Bs[128 * 64];
    const int tid = threadIdx.x;
    const int w = tid >> 6, l = tid & 63;
    const int wr = w >> 1, wc = w & 1;
    const long m0 = (long)blockIdx.y * 128, n0 = (long)blockIdx.x * 128;
    const int lr = l >> 3;
    const int lc = (l & 7) * 8;
    f32x4 acc[4][4];
    #pragma unroll
    for (int s = 0; s < 4; s++)
        #pragma unroll
        for (int n = 0; n < 4; n++) acc[s][n] = (f32x4){0.f, 0.f, 0.f, 0.f};

    for (int k0 = 0; k0 < K; k0 += 64) {
        #pragma unroll
        for (int q = 0; q < 4; q++) {
            int row = w * 32 + q * 8 + lr;
            const ushort_t* g = A + (m0 + row) * (long)K + k0 + lc;
            __builtin_amdgcn_global_load_lds(
                (__attribute__((address_space(1))) unsigned int*)(g),
                (__attribute__((address_space(3))) unsigned int*)(&As[row * 64 + lc]), 16, 0, 0);
        }
        #pragma unroll
        for (int q = 0; q < 4; q++) {
            int row = w * 32 + q * 8 + lr;
            const ushort_t* g = B + (n0 + row) * (long)K + k0 + lc;
            __builtin_amdgcn_global_load_lds(
                (__attribute__((address_space(1))) unsigned int*)(g),
                (__attribute__((address_space(3))) unsigned int*)(&Bs[row * 64 + lc]), 16, 0, 0);
        }
        __syncthreads();
        #pragma unroll
        for (int kk = 0; kk < 2; kk++) {
            f16x8 af[4], bfr[4];
            #pragma unroll
            for (int s = 0; s < 4; s++)
                af[s] = *(const f16x8*)&As[(wr * 64 + s * 16 + (l & 15)) * 64 + kk * 32 + (l >> 4) * 8];
            #pragma unroll
            for (int n = 0; n < 4; n++)
                bfr[n] = *(const f16x8*)&Bs[(wc * 64 + n * 16 + (l & 15)) * 64 + kk * 32 + (l >> 4) * 8];
            #pragma unroll
            for (int s = 0; s < 4; s++)
                #pragma unroll
                for (int n = 0; n < 4; n++)
                    acc[s][n] = __builtin_amdgcn_mfma_f32_16x16x32_f16(af[s], bfr[n], acc[s][n], 0, 0, 0);
        }
        __syncthreads();
    }
    const long rb = m0 + wr * 64 + ((l >> 4) << 2);
    const long cb = n0 + wc * 64 + (l & 15);
    #pragma unroll
    for (int s = 0; s < 4; s++) {
        #pragma unroll
        for (int n = 0; n < 4; n++) {
            long c = cb + n * 16;
            #pragma unroll
            for (int j = 0; j < 4; j++) {
                long r = rb + s * 16 + j;
                float val = acc[s][n][j];
                if constexpr (EPI == 2) {
                    if (r < storeM) {
                        float t = tanhf(val + h2f(bias[c]));
                        Cb[r * ldc + c] = f2h(t);
                    }
                } else {
                    Cb[r * ldc + c] = f2h(val);
                }
            }
        }
    }
}

// ---------------------------------------------------------------------------
// Split-A GEMM for out-layer Z: A = [A0 | A1] (two [.,256] fp16 buffers),
// K = 512 fixed, fp16 store (Z emit). Same tile structure as gemm_bt.
// ---------------------------------------------------------------------------
__global__ __launch_bounds__(256) void gemm_bt2(const ushort_t* __restrict__ A0,
                                                const ushort_t* __restrict__ A1,
                                                const ushort_t* __restrict__ B,
                                                int ldc,
                                                ushort_t* __restrict__ Cb) {
    __shared__ __align__(16) ushort_t As[128 * 64];
    __shared__ __align__(16) ushort_t Bs[128 * 64];
    const int tid = threadIdx.x;
    const int w = tid >> 6, l = tid & 63;
    const int wr = w >> 1, wc = w & 1;
    const long m0 = (long)blockIdx.y * 128, n0 = (long)blockIdx.x * 128;
    const int lr = l >> 3;
    const int lc = (l & 7) * 8;
    f32x4 acc[4][4];
    #pragma unroll
    for (int s = 0; s < 4; s++)
        #pragma unroll
        for (int n = 0; n < 4; n++) acc[s][n] = (f32x4){0.f, 0.f, 0.f, 0.f};

    for (int k0 = 0; k0 < 512; k0 += 64) {
        const ushort_t* Ab = (k0 < 256) ? A0 : A1;
        const int kq = k0 & 255;
        #pragma unroll
        for (int q = 0; q < 4; q++) {
            int row = w * 32 + q * 8 + lr;
            const ushort_t* g = Ab + (m0 + row) * 256L + kq + lc;
            __builtin_amdgcn_global_load_lds(
                (__attribute__((address_space(1))) unsigned int*)(g),
                (__attribute__((address_space(3))) unsigned int*)(&As[row * 64 + lc]), 16, 0, 0);
        }
        #pragma unroll
        for (int q = 0; q < 4; q++) {
            int row = w * 32 + q * 8 + lr;
            const ushort_t* g = B + (n0 + row) * 512L + k0 + lc;
            __builtin_amdgcn_global_load_lds(
                (__attribute__((address_space(1))) unsigned int*)(g),
                (__attribute__((address_space(3))) unsigned int*)(&Bs[row * 64 + lc]), 16, 0, 0);
        }
        __syncthreads();
        #pragma unroll
        for (int kk = 0; kk < 2; kk++) {
            f16x8 af[4], bfr[4];
            #pragma unroll
            for (int s = 0; s < 4; s++)
                af[s] = *(const f16x8*)&As[(wr * 64 + s * 16 + (l & 15)) * 64 + kk * 32 + (l >> 4) * 8];
            #pragma unroll
            for (int n = 0; n < 4; n++)
                bfr[n] = *(const f16x8*)&Bs[(wc * 64 + n * 16 + (l & 15)) * 64 + kk * 32 + (l >> 4) * 8];
            #pragma unroll
            for (int s = 0; s < 4; s++)
                #pragma unroll
                for (int n = 0; n < 4; n++)
                    acc[s][n] = __builtin_amdgcn_mfma_f32_16x16x32_f16(af[s], bfr[n], acc[s][n], 0, 0, 0);
        }
        __syncthreads();
    }
    const long rb = m0 + wr * 64 + ((l >> 4) << 2);
    const long cb = n0 + wc * 64 + (l & 15);
    #pragma unroll
    for (int s = 0; s < 4; s++) {
        #pragma unroll
        for (int n = 0; n < 4; n++) {
            long c = cb + n * 16;
            #pragma unroll
            for (int j = 0; j < 4; j++) {
                long r = rb + s * 16 + j;
                Cb[r * ldc + c] = f2h(acc[s][n][j]);
            }
        }
    }
}

// ---------------------------------------------------------------------------
// Chunk-aggregate over Z (both layer kinds). Z[u, n] fp16, n in [0,512):
//   n = t*64 + oo (agg over src), 256 + t*64 + oo (self, scaled by deg_t(v)).
// M[v, q*64+oo] = sum_{e:tgt=v} Z[src_e, t_e*64+oo] + sum_t D_t(v)*Z[v,256+t*64+oo]
// Wave per node, lane = oo. mld = M row stride (256 inner / 512 out).
// ---------------------------------------------------------------------------
__global__ __launch_bounds__(256) void agg_q(const ushort_t* __restrict__ Z,
                                             const int* __restrict__ offsets,
                                             const int* __restrict__ sorted,
                                             ushort_t* __restrict__ M, int mld, int q) {
    int v = blockIdx.x * 4 + (threadIdx.x >> 6);
    int l = threadIdx.x & 63;
    if (v >= NPAD) return;
    ushort_t* mp = M + (size_t)v * mld + (q << 6) + l;
    if (v >= N_NODES) { *mp = 0; return; }
    float acc = 0.f;
    int d0 = 0, d1 = 0, d2 = 0, d3 = 0;
    int beg = offsets[v], end = offsets[v + 1];
    for (int e = beg; e < end; ++e) {
        int pk = sorted[e];
        int t = pk >> 28;                 // 0..3
        int s = pk & 0x0FFFFFFF;
        acc += h2f(Z[(size_t)s * 512 + (t << 6) + l]);
        d0 += (t == 0); d1 += (t == 1); d2 += (t == 2); d3 += (t == 3);
    }
    const ushort_t* zs = Z + (size_t)v * 512 + 256 + l;
    if (d0) acc += (float)d0 * h2f(zs[0]);
    if (d1) acc += (float)d1 * h2f(zs[64]);
    if (d2) acc += (float)d2 * h2f(zs[128]);
    if (d3) acc += (float)d3 * h2f(zs[192]);
    *mp = f2h(acc);
}

// ---------------------------------------------------------------------------
// gelu (exact erf) + LN from fp16 M. Wave per row, DOUT = 256 or 512.
// ---------------------------------------------------------------------------
template<int DOUT>
__global__ __launch_bounds__(256) void gelu_ln16_k(const ushort_t* __restrict__ M,
                                                   const ushort_t* __restrict__ ls,
                                                   const ushort_t* __restrict__ lb,
                                                   ushort_t* __restrict__ H) {
    constexpr int VPL = DOUT / 64;
    int row = blockIdx.x * 4 + (threadIdx.x >> 6);
    int l = threadIdx.x & 63;
    const ushort_t* mp = M + (size_t)row * DOUT + l * VPL;
    u16x4 mv[VPL / 4];
    #pragma unroll
    for (int c = 0; c < VPL / 4; c++) mv[c] = *(const u16x4*)(mp + c * 4);
    float g[VPL];
    float s = 0.f, q = 0.f;
    #pragma unroll
    for (int i = 0; i < VPL; i++) {
        float x = h2f(mv[i >> 2][i & 3]);
        float gg = 0.5f * x * (1.f + erff(x * 0.70710678118654752f));
        g[i] = gg; s += gg; q += gg * gg;
    }
    #pragma unroll
    for (int m = 1; m < 64; m <<= 1) {
        s += __shfl_xor(s, m, 64);
        q += __shfl_xor(q, m, 64);
    }
    float mean = s * (1.f / DOUT);
    float var = q * (1.f / DOUT) - mean * mean;
    var = fmaxf(var, 0.f);
    float rs = rsqrtf(var + 1e-5f);
    int col = l * VPL;
    ushort_t* hp = H + (size_t)row * DOUT + col;
    #pragma unroll
    for (int i = 0; i < VPL; i++)
        hp[i] = f2h((g[i] - mean) * rs * h2f(ls[col + i]) + h2f(lb[col + i]));
}

// ---------------------------------------------------------------------------
extern "C" void kernel_launch(void* const* d_in, const int* in_sizes, int n_in,
                              void* d_out, int out_size, void* d_ws, size_t ws_size,
                              hipStream_t stream) {
    const int* ids = (const int*)d_in[0];
    const int* te = (const int*)d_in[1];
    const int* et = te;
    const int* esrc = te + NE;
    const int* etgt = te + 2 * NE;
    const void* tab = d_in[2];
    const void* eWi = d_in[3];
    const void* lsi = d_in[4];
    const void* lbi = d_in[5];
    const void* dWi = d_in[6];
    const void* dbi = d_in[7];
    const void* eWo = d_in[8];
    const void* lso = d_in[9];
    const void* lbo = d_in[10];
    const void* dWo = d_in[11];
    const void* dbo = d_in[12];

    char* w = (char*)d_ws;
    auto alloc = [&](size_t bytes) -> char* {
        char* p = w; w += (bytes + 255) & ~(size_t)255; return p;
    };
    ushort_t* A    = (ushort_t*)alloc((size_t)NPAD * 256 * 2);      // 51.25 MB
    ushort_t* Bst  = (ushort_t*)alloc((size_t)NPAD * 256 * 2);      // 51.25 MB
    ushort_t* WC   = (ushort_t*)alloc(7340032UL * 2);               // 14.7 MB
    ushort_t* lsiC = (ushort_t*)alloc(1536 * 2);
    ushort_t* lbiC = (ushort_t*)alloc(1536 * 2);
    ushort_t* dbiC = (ushort_t*)alloc(1536 * 2);
    ushort_t* lsoC = (ushort_t*)alloc(1024 * 2);
    ushort_t* lboC = (ushort_t*)alloc(1024 * 2);
    ushort_t* dboC = (ushort_t*)alloc(512 * 2);
    ushort_t* dWiC = (ushort_t*)alloc(393216UL * 2);
    ushort_t* dWoC = (ushort_t*)alloc(262144UL * 2);
    int* flag      = (int*)alloc(256);
    int* counts    = (int*)alloc((size_t)N_NODES * 4);
    int* incl      = (int*)alloc((size_t)N_NODES * 4);
    int* chsums    = (int*)alloc(1024);
    int* chunkoff  = (int*)alloc(1024);
    int* offsets   = (int*)alloc((size_t)(N_NODES + 8) * 4);
    int* cursor    = (int*)alloc((size_t)N_NODES * 4);
    int* sorted    = (int*)alloc((size_t)NE * 4);
    ushort_t* Magg = (ushort_t*)alloc((size_t)NPAD * 512 * 2);      // 102.5 MB (msg, inner uses 256 cols)
    // Third state buffer: prefer d_out (f32 harness -> 102.4 MB), else ws.
    ushort_t* R;
    if ((size_t)out_size >= (size_t)NPAD * 256 * 2) R = (ushort_t*)d_out;
    else R = (ushort_t*)alloc((size_t)NPAD * 256 * 2);
    size_t fixed = (size_t)(w - (char*)d_ws);

    // Big shared scratch: Zq [NPAD,512] fp16, then H (same address once Zq dead)
    const size_t ZQ_BYTES = (size_t)NPAD * 512 * 2;                 // 102,498,304
    size_t bigsz = (ws_size > fixed) ? (ws_size - fixed) : 0;
    if (bigsz < ZQ_BYTES) {
        fprintf(stderr, "kernel_launch: ws too small (%zu bytes, fixed %zu, big %zu) -- no-op\n",
                ws_size, fixed, bigsz);
        return;
    }
    ushort_t* Zq = (ushort_t*)w;     // [NPAD,512] fp16 chunk
    ushort_t* H  = (ushort_t*)w;     // [NPAD,256/512] fp16 (after Zq dead)

    // ---- setup: dtype detect, canonicalize, CSR, embed, weight pack ----
    detect_k<<<1, 256, 0, stream>>>((const unsigned*)tab, flag);
    CvtArgs ca;
    ca.src[0] = lsi;  ca.dst[0] = lsiC; ca.n[0] = 1536;
    ca.src[1] = lbi;  ca.dst[1] = lbiC; ca.n[1] = 1536;
    ca.src[2] = dbi;  ca.dst[2] = dbiC; ca.n[2] = 1536;
    ca.src[3] = lso;  ca.dst[3] = lsoC; ca.n[3] = 1024;
    ca.src[4] = lbo;  ca.dst[4] = lboC; ca.n[4] = 1024;
    ca.src[5] = dbo;  ca.dst[5] = dboC; ca.n[5] = 512;
    ca.src[6] = dWi;  ca.dst[6] = dWiC; ca.n[6] = 393216;
    ca.src[7] = dWo;  ca.dst[7] = dWoC; ca.n[7] = 262144;
    cvt_k<<<dim3(1536, 8), 256, 0, stream>>>(ca, flag);
    hipMemsetAsync(counts, 0, (size_t)N_NODES * 4, stream);
    // zero pad rows (100000..100095) of the three state buffers once
    hipMemsetAsync(A   + (size_t)N_NODES * 256, 0, (size_t)(NPAD - N_NODES) * 256 * 2, stream);
    hipMemsetAsync(Bst + (size_t)N_NODES * 256, 0, (size_t)(NPAD - N_NODES) * 256 * 2, stream);
    hipMemsetAsync(R   + (size_t)N_NODES * 256, 0, (size_t)(NPAD - N_NODES) * 256 * 2, stream);
    pack_w<<<28672, 256, 0, stream>>>(eWi, eWo, WC, flag);
    embed_k<<<N_NODES / 4, 256, 0, stream>>>(ids, tab, A, flag);
    count_k<<<(NE + 255) / 256, 256, 0, stream>>>(etgt, counts);
    scan1_k<<<NCH, 256, 0, stream>>>(counts, incl, chsums);
    scan2_k<<<1, 256, 0, stream>>>(chsums, chunkoff);
    scan3_k<<<NCH, 256, 0, stream>>>(counts, incl, chunkoff, offsets, cursor);
    fill_k<<<(NE + 255) / 256, 256, 0, stream>>>(et, esrc, etgt, cursor, sorted);

    // ---- inner layer (transform-then-aggregate, quarter-chunked Z) ----
    auto inner_layer = [&](const ushort_t* Xin, ushort_t* Xout, int lay) {
        for (int q = 0; q < 4; q++) {
            gemm_bt<3><<<dim3(4, NTILES), 256, 0, stream>>>(
                Xin, WC + (long)lay * 524288 + (long)q * 131072, 256, 512, Zq, nullptr, 0);
            agg_q<<<NPAD / 4, 256, 0, stream>>>(Zq, offsets, sorted, Magg, 256, q);
        }
        gelu_ln16_k<256><<<NPAD / 4, 256, 0, stream>>>(Magg, lsiC + lay * 256, lbiC + lay * 256, H);
        gemm_bt<2><<<dim3(2, NTILES), 256, 0, stream>>>(H, dWiC + (long)lay * 65536, 256, 256,
                                                        Xout, dbiC + lay * 256, N_NODES);
    };

    // ---- out layer (transform-then-aggregate, eighth-chunked Z, split-A) ----
    auto out_layer = [&](const ushort_t* X0, const ushort_t* X1, int b, ushort_t* dest) {
        for (int c = 0; c < 8; c++) {
            gemm_bt2<<<dim3(4, NTILES), 256, 0, stream>>>(
                X0, X1, WC + WCO_OFF + (long)b * 2097152 + (long)c * 262144, 512, Zq);
            agg_q<<<NPAD / 4, 256, 0, stream>>>(Zq, offsets, sorted, Magg, 512, c);
        }
        gelu_ln16_k<512><<<NPAD / 4, 256, 0, stream>>>(Magg, lsoC + b * 512, lboC + b * 512, H);
        gemm_bt<2><<<dim3(2, NTILES), 256, 0, stream>>>(H, dWoC + (long)b * 131072, 512, 256,
                                                        dest, dboC + b * 256, N_NODES);
    };

    // block 0: state A (embed). inner: A->Bst, Bst->R, R->Bst. out [A|Bst] -> R
    inner_layer(A, Bst, 0);
    inner_layer(Bst, R, 1);
    inner_layer(R, Bst, 2);
    out_layer(A, Bst, 0, R);
    // block 1: state R. inner: R->A, A->Bst, Bst->A. out [R|A] -> Bst
    inner_layer(R, A, 3);
    inner_layer(A, Bst, 4);
    inner_layer(Bst, A, 5);
    out_layer(R, A, 1, Bst);

    emit_k<<<(OUT_ELEMS + 255) / 256, 256, 0, stream>>>(Bst, d_out, flag);
}

// Round 5
// 6237.302 us; speedup vs baseline: 1.1393x; 1.0404x over previous
//
#include <hip/hip_runtime.h>
#include <cstdio>

#define N_NODES 100000
#define NPAD    100096      // 782*128 padded row count (gemm reads full tiles)
#define NTILES  782         // ceil(100000/128)
#define NE      320000
#define NCH     196         // ceil(100000/512)
#define WCO_OFF 3145728L    // 6*256*2048 inner W elems (quarter-Z layout)
#define OUT_ELEMS (N_NODES * 256)

typedef unsigned short ushort_t;
typedef unsigned short u16x4 __attribute__((ext_vector_type(4)));
typedef unsigned short u16x8 __attribute__((ext_vector_type(8)));
typedef _Float16       f16;
typedef _Float16       f16x8 __attribute__((ext_vector_type(8)));
typedef float          f32x4 __attribute__((ext_vector_type(4)));
typedef float          f32x4v __attribute__((ext_vector_type(4)));

__device__ __forceinline__ float bf2f(ushort_t u) {
    return __uint_as_float(((unsigned)u) << 16);
}
__device__ __forceinline__ ushort_t f2bf(float f) {
    unsigned u = __float_as_uint(f);
    u += 0x7FFFu + ((u >> 16) & 1u);   // round-to-nearest-even
    return (ushort_t)(u >> 16);
}
__device__ __forceinline__ ushort_t f2h(float f) {
    f16 h = (f16)f;
    return __builtin_bit_cast(ushort_t, h);
}
__device__ __forceinline__ float h2f(ushort_t u) {
    return (float)__builtin_bit_cast(f16, u);
}

// ---------------------------------------------------------------------------
// XCD-aware bijective block remap (m204 variant; handles nwg % 8 != 0).
// Physical blocks {k, k+8, ...} (dispatched to XCD k) process consecutive
// logical tiles -> col-blocks sharing an A row-panel co-reside on one L2.
// ---------------------------------------------------------------------------
__device__ __forceinline__ int xcd_remap(int pbid, int nwg) {
    int q = nwg >> 3, r = nwg & 7;
    int xcd = pbid & 7, idx = pbid >> 3;
    int base = (xcd < r) ? xcd * (q + 1) : r * (q + 1) + (xcd - r) * q;
    return base + idx;
}

// fast tanh: clamp + exp identity (abs err ~1e-6, invisible in fp16)
__device__ __forceinline__ float fast_tanh(float x) {
    x = fminf(fmaxf(x, -10.f), 10.f);
    float e = __expf(2.f * x);
    return (e - 1.f) / (e + 1.f);
}

// ---------------------------------------------------------------------------
// dtype sniff on embed_table words. flag = 1 means float32 inputs.
// ---------------------------------------------------------------------------
__global__ __launch_bounds__(256) void detect_k(const unsigned* __restrict__ w0, int* __restrict__ flag) {
    __shared__ int lds[256];
    int t = threadIdx.x;
    int cnt = 0;
    for (int i = t; i < 2048; i += 256) {
        unsigned e = (w0[i] >> 7) & 0xFFu;
        cnt += (e >= 96u && e <= 140u) ? 1 : 0;
    }
    lds[t] = cnt; __syncthreads();
    for (int s = 128; s > 0; s >>= 1) {
        if (t < s) lds[t] += lds[t + s];
        __syncthreads();
    }
    if (t == 0) *flag = (lds[0] < 1024) ? 1 : 0;
}

// input element -> canonical fp16 bits
__device__ __forceinline__ ushort_t load_in(const void* p, long i, bool isf32) {
    return isf32 ? f2h(((const float*)p)[i]) : f2h(bf2f(((const ushort_t*)p)[i]));
}

// ---------------------------------------------------------------------------
// small-tensor fp16 canonicalization (ln scales/biases, dense W/b)
// ---------------------------------------------------------------------------
struct CvtArgs {
    const void* src[8];
    ushort_t*   dst[8];
    int         n[8];
};

__global__ __launch_bounds__(256) void cvt_k(CvtArgs a, const int* __restrict__ flag) {
    int ti = blockIdx.y;
    int n = a.n[ti];
    const void* s = a.src[ti];
    ushort_t* d = a.dst[ti];
    bool isf32 = (*flag != 0);
    for (int i = blockIdx.x * 256 + threadIdx.x; i < n; i += gridDim.x * 256)
        d[i] = load_in(s, i, isf32);
}

// ---------------------------------------------------------------------------
// Weight pre-pack (dual dtype -> fp16), both stacks in quarter-Z layout.
// INNER: layer l, chunk q (out cols o = q*64+oo), slab WC[l*524288 + q*131072
//   + n*256 + k], n in [0,512): n = t*64+oo (agg, j=k<256) ; 256+t*64+oo (self, j=256+k)
// OUTER: block b, chunk c (out cols o = c*64+oo), slab WC[WCO_OFF + b*2097152
//   + c*262144 + n*512 + k], n in [0,512): n = t*64+oo (agg/src, j=k<512) ;
//   256+t*64+oo (self/tgt, j=512+k)
// ---------------------------------------------------------------------------
__global__ __launch_bounds__(256) void pack_w(const void* __restrict__ eWi,
                                              const void* __restrict__ eWo,
                                              ushort_t* __restrict__ WC,
                                              const int* __restrict__ flag) {
    long idx = (long)blockIdx.x * 256 + threadIdx.x;
    bool isf32 = (*flag != 0);
    const long ELI = 6L * 4 * 256 * 512;     // 3,145,728
    const long ELO = 2L * 4 * 512 * 1024;    // 4,194,304
    if (idx < ELI) {
        int j = idx & 511;
        int o = (idx >> 9) & 255;
        int t = (idx >> 17) & 3;
        long l = idx >> 19;
        int q = o >> 6, oo = o & 63;
        int k = j & 255;
        int n = ((j < 256) ? 0 : 256) + t * 64 + oo;
        WC[l * 524288 + (long)q * 131072 + (long)n * 256 + k] = load_in(eWi, idx, isf32);
    } else if (idx < ELI + ELO) {
        long i2 = idx - ELI;
        int j = i2 & 1023;
        int o = (i2 >> 10) & 511;
        int t = (i2 >> 19) & 3;
        long b = i2 >> 21;
        int c = o >> 6, oo = o & 63;
        int k = j & 511;
        int n = ((j < 512) ? 0 : 256) + t * 64 + oo;
        WC[WCO_OFF + b * 2097152L + (long)c * 262144 + (long)n * 512 + k] = load_in(eWo, i2, isf32);
    }
}

// ---------------------------------------------------------------------------
// Embedding gather (dual dtype): S[v] = fp16(table[ids[v]])
// ---------------------------------------------------------------------------
__global__ __launch_bounds__(256) void embed_k(const int* __restrict__ ids,
                                               const void* __restrict__ tab,
                                               ushort_t* __restrict__ S,
                                               const int* __restrict__ flag) {
    int row = blockIdx.x * 4 + (threadIdx.x >> 6);
    int l = threadIdx.x & 63;
    if (row >= N_NODES) return;
    int id = ids[row];
    u16x4 v;
    if (*flag) {
        f32x4v fv = *(const f32x4v*)((const float*)tab + (size_t)id * 256 + l * 4);
        #pragma unroll
        for (int i = 0; i < 4; i++) v[i] = f2h(fv[i]);
    } else {
        u16x4 bv = *(const u16x4*)((const ushort_t*)tab + (size_t)id * 256 + l * 4);
        #pragma unroll
        for (int i = 0; i < 4; i++) v[i] = f2h(bf2f(bv[i]));
    }
    *(u16x4*)(S + (size_t)row * 256 + l * 4) = v;
}

// ---------------------------------------------------------------------------
// Output emit: internal fp16 -> harness dtype (f32 or bf16)
// ---------------------------------------------------------------------------
__global__ __launch_bounds__(256) void emit_k(const ushort_t* __restrict__ Bst, void* __restrict__ out,
                                              const int* __restrict__ flag) {
    long i = (long)blockIdx.x * 256 + threadIdx.x;
    if (i >= OUT_ELEMS) return;
    float v = h2f(Bst[i]);
    if (*flag) ((float*)out)[i] = v;
    else       ((ushort_t*)out)[i] = f2bf(v);
}

// ---------------------------------------------------------------------------
// CSR by target node
// ---------------------------------------------------------------------------
__global__ __launch_bounds__(256) void count_k(const int* __restrict__ tgt, int* __restrict__ counts) {
    int e = blockIdx.x * 256 + threadIdx.x;
    if (e < NE) atomicAdd(&counts[tgt[e]], 1);
}

__global__ __launch_bounds__(256) void scan1_k(const int* __restrict__ counts,
                                               int* __restrict__ incl, int* __restrict__ chsums) {
    __shared__ int lds[256];
    int c = blockIdx.x, t = threadIdx.x;
    int i0 = c * 512 + 2 * t;
    int a = (i0 < N_NODES) ? counts[i0] : 0;
    int b = (i0 + 1 < N_NODES) ? counts[i0 + 1] : 0;
    int ps = a + b;
    lds[t] = ps; __syncthreads();
    int x = ps;
    for (int off = 1; off < 256; off <<= 1) {
        int y = (t >= off) ? lds[t - off] : 0;
        __syncthreads();
        x += y; lds[t] = x;
        __syncthreads();
    }
    int excl = x - ps;
    if (i0 < N_NODES) incl[i0] = excl + a;
    if (i0 + 1 < N_NODES) incl[i0 + 1] = excl + a + b;
    if (t == 255) chsums[c] = x;
}

__global__ __launch_bounds__(256) void scan2_k(const int* __restrict__ chsums, int* __restrict__ chunkoff) {
    __shared__ int lds[256];
    int t = threadIdx.x;
    int v = (t < NCH) ? chsums[t] : 0;
    lds[t] = v; __syncthreads();
    int x = v;
    for (int off = 1; off < 256; off <<= 1) {
        int y = (t >= off) ? lds[t - off] : 0;
        __syncthreads();
        x += y; lds[t] = x;
        __syncthreads();
    }
    if (t <= NCH) chunkoff[t] = x - v;   // exclusive
}

__global__ __launch_bounds__(256) void scan3_k(const int* __restrict__ counts, const int* __restrict__ incl,
                                               const int* __restrict__ chunkoff,
                                               int* __restrict__ offsets, int* __restrict__ cursor) {
    int c = blockIdx.x, t = threadIdx.x;
    int base = chunkoff[c];
    #pragma unroll
    for (int k = 0; k < 2; k++) {
        int i = c * 512 + 2 * t + k;
        if (i < N_NODES) {
            int off = base + incl[i] - counts[i];
            offsets[i] = off;
            cursor[i] = off;
        }
    }
    if (c == 0 && t == 0) offsets[N_NODES] = chunkoff[NCH];
}

__global__ __launch_bounds__(256) void fill_k(const int* __restrict__ et, const int* __restrict__ src,
                                              const int* __restrict__ tgt,
                                              int* __restrict__ cursor, int* __restrict__ sorted) {
    int e = blockIdx.x * 256 + threadIdx.x;
    if (e < NE) {
        int pos = atomicAdd(&cursor[tgt[e]], 1);
        sorted[pos] = ((et[e] - 1) << 28) | src[e];
    }
}

// ---------------------------------------------------------------------------
// GEMM: C[localM, ldc] = A[localM, K] @ B[., K]^T  (fp16 row-major)
// 128x128 tile, BK=64, 4 waves, mfma_f32_16x16x32_f16, global_load_lds(16B).
// XCD-remapped block order for A-panel L2 reuse.
// EPI 2: Cb[r*ldc+c] = fp16(tanh(acc + bias[c])), local rows < storeM only
// EPI 3: Cb[r*ldc+c] = fp16(acc)                (Z emit, unguarded/padded)
// ---------------------------------------------------------------------------
template<int EPI>
__global__ __launch_bounds__(256) void gemm_bt(const ushort_t* __restrict__ A,
                                               const ushort_t* __restrict__ B,
                                               int K, int ldc,
                                               ushort_t* __restrict__ Cb,
                                               const ushort_t* __restrict__ bias, int storeM) {
    __shared__ __align__(16) ushort_t As[128 * 64];
    __shared__ __align__(16) ushort_t Bs[128 * 64];
    const int tid = threadIdx.x;
    const int w = tid >> 6, l = tid & 63;
    const int wr = w >> 1, wc = w & 1;
    const int gx = gridDim.x;
    const int lbid = xcd_remap(blockIdx.y * gx + blockIdx.x, gx * gridDim.y);
    const long m0 = (long)(lbid / gx) * 128, n0 = (long)(lbid % gx) * 128;
    const int lr = l >> 3;
    const int lc = (l & 7) * 8;
    f32x4 acc[4][4];
    #pragma unroll
    for (int s = 0; s < 4; s++)
        #pragma unroll
        for (int n = 0; n < 4; n++) acc[s][n] = (f32x4){0.f, 0.f, 0.f, 0.f};

    for (int k0 = 0; k0 < K; k0 += 64) {
        #pragma unroll
        for (int q = 0; q < 4; q++) {
            int row = w * 32 + q * 8 + lr;
            const ushort_t* g = A + (m0 + row) * (long)K + k0 + lc;
            __builtin_amdgcn_global_load_lds(
                (__attribute__((address_space(1))) unsigned int*)(g),
                (__attribute__((address_space(3))) unsigned int*)(&As[row * 64 + lc]), 16, 0, 0);
        }
        #pragma unroll
        for (int q = 0; q < 4; q++) {
            int row = w * 32 + q * 8 + lr;
            const ushort_t* g = B + (n0 + row) * (long)K + k0 + lc;
            __builtin_amdgcn_global_load_lds(
                (__attribute__((address_space(1))) unsigned int*)(g),
                (__attribute__((address_space(3))) unsigned int*)(&Bs[row * 64 + lc]), 16, 0, 0);
        }
        __syncthreads();
        #pragma unroll
        for (int kk = 0; kk < 2; kk++) {
            f16x8 af[4], bfr[4];
            #pragma unroll
            for (int s = 0; s < 4; s++)
                af[s] = *(const f16x8*)&As[(wr * 64 + s * 16 + (l & 15)) * 64 + kk * 32 + (l >> 4) * 8];
            #pragma unroll
            for (int n = 0; n < 4; n++)
                bfr[n] = *(const f16x8*)&Bs[(wc * 64 + n * 16 + (l & 15)) * 64 + kk * 32 + (l >> 4) * 8];
            #pragma unroll
            for (int s = 0; s < 4; s++)
                #pragma unroll
                for (int n = 0; n < 4; n++)
                    acc[s][n] = __builtin_amdgcn_mfma_f32_16x16x32_f16(af[s], bfr[n], acc[s][n], 0, 0, 0);
        }
        __syncthreads();
    }
    const long rb = m0 + wr * 64 + ((l >> 4) << 2);
    const long cb = n0 + wc * 64 + (l & 15);
    #pragma unroll
    for (int s = 0; s < 4; s++) {
        #pragma unroll
        for (int n = 0; n < 4; n++) {
            long c = cb + n * 16;
            #pragma unroll
            for (int j = 0; j < 4; j++) {
                long r = rb + s * 16 + j;
                float val = acc[s][n][j];
                if constexpr (EPI == 2) {
                    if (r < storeM) {
                        float t = fast_tanh(val + h2f(bias[c]));
                        Cb[r * ldc + c] = f2h(t);
                    }
                } else {
                    Cb[r * ldc + c] = f2h(val);
                }
            }
        }
    }
}

// ---------------------------------------------------------------------------
// Split-A GEMM for out-layer Z: A = [A0 | A1] (two [.,256] fp16 buffers),
// K = 512 fixed, fp16 store (Z emit). XCD-remapped. Same tile structure.
// ---------------------------------------------------------------------------
__global__ __launch_bounds__(256) void gemm_bt2(const ushort_t* __restrict__ A0,
                                                const ushort_t* __restrict__ A1,
                                                const ushort_t* __restrict__ B,
                                                int ldc,
                                                ushort_t* __restrict__ Cb) {
    __shared__ __align__(16) ushort_t As[128 * 64];
    __shared__ __align__(16) ushort_t Bs[128 * 64];
    const int tid = threadIdx.x;
    const int w = tid >> 6, l = tid & 63;
    const int wr = w >> 1, wc = w & 1;
    const int gx = gridDim.x;
    const int lbid = xcd_remap(blockIdx.y * gx + blockIdx.x, gx * gridDim.y);
    const long m0 = (long)(lbid / gx) * 128, n0 = (long)(lbid % gx) * 128;
    const int lr = l >> 3;
    const int lc = (l & 7) * 8;
    f32x4 acc[4][4];
    #pragma unroll
    for (int s = 0; s < 4; s++)
        #pragma unroll
        for (int n = 0; n < 4; n++) acc[s][n] = (f32x4){0.f, 0.f, 0.f, 0.f};

    for (int k0 = 0; k0 < 512; k0 += 64) {
        const ushort_t* Ab = (k0 < 256) ? A0 : A1;
        const int kq = k0 & 255;
        #pragma unroll
        for (int q = 0; q < 4; q++) {
            int row = w * 32 + q * 8 + lr;
            const ushort_t* g = Ab + (m0 + row) * 256L + kq + lc;
            __builtin_amdgcn_global_load_lds(
                (__attribute__((address_space(1))) unsigned int*)(g),
                (__attribute__((address_space(3))) unsigned int*)(&As[row * 64 + lc]), 16, 0, 0);
        }
        #pragma unroll
        for (int q = 0; q < 4; q++) {
            int row = w * 32 + q * 8 + lr;
            const ushort_t* g = B + (n0 + row) * 512L + k0 + lc;
            __builtin_amdgcn_global_load_lds(
                (__attribute__((address_space(1))) unsigned int*)(g),
                (__attribute__((address_space(3))) unsigned int*)(&Bs[row * 64 + lc]), 16, 0, 0);
        }
        __syncthreads();
        #pragma unroll
        for (int kk = 0; kk < 2; kk++) {
            f16x8 af[4], bfr[4];
            #pragma unroll
            for (int s = 0; s < 4; s++)
                af[s] = *(const f16x8*)&As[(wr * 64 + s * 16 + (l & 15)) * 64 + kk * 32 + (l >> 4) * 8];
            #pragma unroll
            for (int n = 0; n < 4; n++)
                bfr[n] = *(const f16x8*)&Bs[(wc * 64 + n * 16 + (l & 15)) * 64 + kk * 32 + (l >> 4) * 8];
            #pragma unroll
            for (int s = 0; s < 4; s++)
                #pragma unroll
                for (int n = 0; n < 4; n++)
                    acc[s][n] = __builtin_amdgcn_mfma_f32_16x16x32_f16(af[s], bfr[n], acc[s][n], 0, 0, 0);
        }
        __syncthreads();
    }
    const long rb = m0 + wr * 64 + ((l >> 4) << 2);
    const long cb = n0 + wc * 64 + (l & 15);
    #pragma unroll
    for (int s = 0; s < 4; s++) {
        #pragma unroll
        for (int n = 0; n < 4; n++) {
            long c = cb + n * 16;
            #pragma unroll
            for (int j = 0; j < 4; j++) {
                long r = rb + s * 16 + j;
                Cb[r * ldc + c] = f2h(acc[s][n][j]);
            }
        }
    }
}

// ---------------------------------------------------------------------------
// Chunk-aggregate over Z (both layer kinds). Z[u, n] fp16, n in [0,512):
//   n = t*64 + oo (agg over src), 256 + t*64 + oo (self, scaled by deg_t(v)).
// M[v, q*64+oo] = sum_{e:tgt=v} Z[src_e, t_e*64+oo] + sum_t D_t(v)*Z[v,256+t*64+oo]
// Wave per node, lane = oo. mld = M row stride (256 inner / 512 out).
// ---------------------------------------------------------------------------
__global__ __launch_bounds__(256) void agg_q(const ushort_t* __restrict__ Z,
                                             const int* __restrict__ offsets,
                                             const int* __restrict__ sorted,
                                             ushort_t* __restrict__ M, int mld, int q) {
    int v = blockIdx.x * 4 + (threadIdx.x >> 6);
    int l = threadIdx.x & 63;
    if (v >= NPAD) return;
    ushort_t* mp = M + (size_t)v * mld + (q << 6) + l;
    if (v >= N_NODES) { *mp = 0; return; }
    float acc = 0.f;
    int d0 = 0, d1 = 0, d2 = 0, d3 = 0;
    int beg = offsets[v], end = offsets[v + 1];
    for (int e = beg; e < end; ++e) {
        int pk = sorted[e];
        int t = pk >> 28;                 // 0..3
        int s = pk & 0x0FFFFFFF;
        acc += h2f(Z[(size_t)s * 512 + (t << 6) + l]);
        d0 += (t == 0); d1 += (t == 1); d2 += (t == 2); d3 += (t == 3);
    }
    const ushort_t* zs = Z + (size_t)v * 512 + 256 + l;
    if (d0) acc += (float)d0 * h2f(zs[0]);
    if (d1) acc += (float)d1 * h2f(zs[64]);
    if (d2) acc += (float)d2 * h2f(zs[128]);
    if (d3) acc += (float)d3 * h2f(zs[192]);
    *mp = f2h(acc);
}

// ---------------------------------------------------------------------------
// gelu (exact erf) + LN from fp16 M. Wave per row, DOUT = 256 or 512.
// ---------------------------------------------------------------------------
template<int DOUT>
__global__ __launch_bounds__(256) void gelu_ln16_k(const ushort_t* __restrict__ M,
                                                   const ushort_t* __restrict__ ls,
                                                   const ushort_t* __restrict__ lb,
                                                   ushort_t* __restrict__ H) {
    constexpr int VPL = DOUT / 64;
    int row = blockIdx.x * 4 + (threadIdx.x >> 6);
    int l = threadIdx.x & 63;
    const ushort_t* mp = M + (size_t)row * DOUT + l * VPL;
    u16x4 mv[VPL / 4];
    #pragma unroll
    for (int c = 0; c < VPL / 4; c++) mv[c] = *(const u16x4*)(mp + c * 4);
    float g[VPL];
    float s = 0.f, q = 0.f;
    #pragma unroll
    for (int i = 0; i < VPL; i++) {
        float x = h2f(mv[i >> 2][i & 3]);
        float gg = 0.5f * x * (1.f + erff(x * 0.70710678118654752f));
        g[i] = gg; s += gg; q += gg * gg;
    }
    #pragma unroll
    for (int m = 1; m < 64; m <<= 1) {
        s += __shfl_xor(s, m, 64);
        q += __shfl_xor(q, m, 64);
    }
    float mean = s * (1.f / DOUT);
    float var = q * (1.f / DOUT) - mean * mean;
    var = fmaxf(var, 0.f);
    float rs = rsqrtf(var + 1e-5f);
    int col = l * VPL;
    ushort_t* hp = H + (size_t)row * DOUT + col;
    #pragma unroll
    for (int i = 0; i < VPL; i++)
        hp[i] = f2h((g[i] - mean) * rs * h2f(ls[col + i]) + h2f(lb[col + i]));
}

// ---------------------------------------------------------------------------
extern "C" void kernel_launch(void* const* d_in, const int* in_sizes, int n_in,
                              void* d_out, int out_size, void* d_ws, size_t ws_size,
                              hipStream_t stream) {
    const int* ids = (const int*)d_in[0];
    const int* te = (const int*)d_in[1];
    const int* et = te;
    const int* esrc = te + NE;
    const int* etgt = te + 2 * NE;
    const void* tab = d_in[2];
    const void* eWi = d_in[3];
    const void* lsi = d_in[4];
    const void* lbi = d_in[5];
    const void* dWi = d_in[6];
    const void* dbi = d_in[7];
    const void* eWo = d_in[8];
    const void* lso = d_in[9];
    const void* lbo = d_in[10];
    const void* dWo = d_in[11];
    const void* dbo = d_in[12];

    char* w = (char*)d_ws;
    auto alloc = [&](size_t bytes) -> char* {
        char* p = w; w += (bytes + 255) & ~(size_t)255; return p;
    };
    ushort_t* A    = (ushort_t*)alloc((size_t)NPAD * 256 * 2);      // 51.25 MB
    ushort_t* Bst  = (ushort_t*)alloc((size_t)NPAD * 256 * 2);      // 51.25 MB
    ushort_t* WC   = (ushort_t*)alloc(7340032UL * 2);               // 14.7 MB
    ushort_t* lsiC = (ushort_t*)alloc(1536 * 2);
    ushort_t* lbiC = (ushort_t*)alloc(1536 * 2);
    ushort_t* dbiC = (ushort_t*)alloc(1536 * 2);
    ushort_t* lsoC = (ushort_t*)alloc(1024 * 2);
    ushort_t* lboC = (ushort_t*)alloc(1024 * 2);
    ushort_t* dboC = (ushort_t*)alloc(512 * 2);
    ushort_t* dWiC = (ushort_t*)alloc(393216UL * 2);
    ushort_t* dWoC = (ushort_t*)alloc(262144UL * 2);
    int* flag      = (int*)alloc(256);
    int* counts    = (int*)alloc((size_t)N_NODES * 4);
    int* incl      = (int*)alloc((size_t)N_NODES * 4);
    int* chsums    = (int*)alloc(1024);
    int* chunkoff  = (int*)alloc(1024);
    int* offsets   = (int*)alloc((size_t)(N_NODES + 8) * 4);
    int* cursor    = (int*)alloc((size_t)N_NODES * 4);
    int* sorted    = (int*)alloc((size_t)NE * 4);
    ushort_t* Magg = (ushort_t*)alloc((size_t)NPAD * 512 * 2);      // 102.5 MB (msg, inner uses 256 cols)
    // Third state buffer: prefer d_out (f32 harness -> 102.4 MB), else ws.
    ushort_t* R;
    if ((size_t)out_size >= (size_t)NPAD * 256 * 2) R = (ushort_t*)d_out;
    else R = (ushort_t*)alloc((size_t)NPAD * 256 * 2);
    size_t fixed = (size_t)(w - (char*)d_ws);

    // Big shared scratch: Zq [NPAD,512] fp16, then H (same address once Zq dead)
    const size_t ZQ_BYTES = (size_t)NPAD * 512 * 2;                 // 102,498,304
    size_t bigsz = (ws_size > fixed) ? (ws_size - fixed) : 0;
    if (bigsz < ZQ_BYTES) {
        fprintf(stderr, "kernel_launch: ws too small (%zu bytes, fixed %zu, big %zu) -- no-op\n",
                ws_size, fixed, bigsz);
        return;
    }
    ushort_t* Zq = (ushort_t*)w;     // [NPAD,512] fp16 chunk
    ushort_t* H  = (ushort_t*)w;     // [NPAD,256/512] fp16 (after Zq dead)

    // ---- setup: dtype detect, canonicalize, CSR, embed, weight pack ----
    detect_k<<<1, 256, 0, stream>>>((const unsigned*)tab, flag);
    CvtArgs ca;
    ca.src[0] = lsi;  ca.dst[0] = lsiC; ca.n[0] = 1536;
    ca.src[1] = lbi;  ca.dst[1] = lbiC; ca.n[1] = 1536;
    ca.src[2] = dbi;  ca.dst[2] = dbiC; ca.n[2] = 1536;
    ca.src[3] = lso;  ca.dst[3] = lsoC; ca.n[3] = 1024;
    ca.src[4] = lbo;  ca.dst[4] = lboC; ca.n[4] = 1024;
    ca.src[5] = dbo;  ca.dst[5] = dboC; ca.n[5] = 512;
    ca.src[6] = dWi;  ca.dst[6] = dWiC; ca.n[6] = 393216;
    ca.src[7] = dWo;  ca.dst[7] = dWoC; ca.n[7] = 262144;
    cvt_k<<<dim3(1536, 8), 256, 0, stream>>>(ca, flag);
    hipMemsetAsync(counts, 0, (size_t)N_NODES * 4, stream);
    // zero pad rows (100000..100095) of the three state buffers once
    hipMemsetAsync(A   + (size_t)N_NODES * 256, 0, (size_t)(NPAD - N_NODES) * 256 * 2, stream);
    hipMemsetAsync(Bst + (size_t)N_NODES * 256, 0, (size_t)(NPAD - N_NODES) * 256 * 2, stream);
    hipMemsetAsync(R   + (size_t)N_NODES * 256, 0, (size_t)(NPAD - N_NODES) * 256 * 2, stream);
    pack_w<<<28672, 256, 0, stream>>>(eWi, eWo, WC, flag);
    embed_k<<<N_NODES / 4, 256, 0, stream>>>(ids, tab, A, flag);
    count_k<<<(NE + 255) / 256, 256, 0, stream>>>(etgt, counts);
    scan1_k<<<NCH, 256, 0, stream>>>(counts, incl, chsums);
    scan2_k<<<1, 256, 0, stream>>>(chsums, chunkoff);
    scan3_k<<<NCH, 256, 0, stream>>>(counts, incl, chunkoff, offsets, cursor);
    fill_k<<<(NE + 255) / 256, 256, 0, stream>>>(et, esrc, etgt, cursor, sorted);

    // ---- inner layer (transform-then-aggregate, quarter-chunked Z) ----
    auto inner_layer = [&](const ushort_t* Xin, ushort_t* Xout, int lay) {
        for (int q = 0; q < 4; q++) {
            gemm_bt<3><<<dim3(4, NTILES), 256, 0, stream>>>(
                Xin, WC + (long)lay * 524288 + (long)q * 131072, 256, 512, Zq, nullptr, 0);
            agg_q<<<NPAD / 4, 256, 0, stream>>>(Zq, offsets, sorted, Magg, 256, q);
        }
        gelu_ln16_k<256><<<NPAD / 4, 256, 0, stream>>>(Magg, lsiC + lay * 256, lbiC + lay * 256, H);
        gemm_bt<2><<<dim3(2, NTILES), 256, 0, stream>>>(H, dWiC + (long)lay * 65536, 256, 256,
                                                        Xout, dbiC + lay * 256, N_NODES);
    };

    // ---- out layer (transform-then-aggregate, eighth-chunked Z, split-A) ----
    auto out_layer = [&](const ushort_t* X0, const ushort_t* X1, int b, ushort_t* dest) {
        for (int c = 0; c < 8; c++) {
            gemm_bt2<<<dim3(4, NTILES), 256, 0, stream>>>(
                X0, X1, WC + WCO_OFF + (long)b * 2097152 + (long)c * 262144, 512, Zq);
            agg_q<<<NPAD / 4, 256, 0, stream>>>(Zq, offsets, sorted, Magg, 512, c);
        }
        gelu_ln16_k<512><<<NPAD / 4, 256, 0, stream>>>(Magg, lsoC + b * 512, lboC + b * 512, H);
        gemm_bt<2><<<dim3(2, NTILES), 256, 0, stream>>>(H, dWoC + (long)b * 131072, 512, 256,
                                                        dest, dboC + b * 256, N_NODES);
    };

    // block 0: state A (embed). inner: A->Bst, Bst->R, R->Bst. out [A|Bst] -> R
    inner_layer(A, Bst, 0);
    inner_layer(Bst, R, 1);
    inner_layer(R, Bst, 2);
    out_layer(A, Bst, 0, R);
    // block 1: state R. inner: R->A, A->Bst, Bst->A. out [R|A] -> Bst
    inner_layer(R, A, 3);
    inner_layer(A, Bst, 4);
    inner_layer(Bst, A, 5);
    out_layer(R, A, 1, Bst);

    emit_k<<<(OUT_ELEMS + 255) / 256, 256, 0, stream>>>(Bst, d_out, flag);
}